// Round 1
// baseline (9105.475 us; speedup 1.0000x reference)
//
#include <hip/hip_runtime.h>
#include <math.h>

// Problem constants
#define DD   512
#define LSEQ 2048
#define NBAT 16
#define RTOT (NBAT * LSEQ)   // 32768 rows
#define WREC 8               // workgroups in recurrence

typedef __attribute__((ext_vector_type(8))) short bf16x8;
typedef __attribute__((ext_vector_type(4))) float f32x4;

#define AS1(p) ((const __attribute__((address_space(1))) void*)(p))
#define AS3(p) ((__attribute__((address_space(3))) void*)(p))
#define MFMA16 __builtin_amdgcn_mfma_f32_16x16x32_bf16

__device__ __forceinline__ unsigned short f2bf(float f) {
  unsigned u = __builtin_bit_cast(unsigned, f);
  u += 0x7fffu + ((u >> 16) & 1u);
  return (unsigned short)(u >> 16);
}

// ---------------------------------------------------------------------------
// prep: fold BN into Wx (Wx' = Wx*diag(inv), b' = Wx(beta-mean*inv)+b_rnn),
// convert Wffn to bf16.  blocks 0..511: Wx' row + b' ; blocks 512..1535: Wffn.
// ---------------------------------------------------------------------------
__global__ __launch_bounds__(256) void prep_kernel(
    const float* __restrict__ Wx, const float* __restrict__ gamma,
    const float* __restrict__ beta, const float* __restrict__ mean,
    const float* __restrict__ var, const float* __restrict__ brnn,
    const float* __restrict__ Wffn,
    unsigned short* __restrict__ Wxp, unsigned short* __restrict__ Wfb,
    float* __restrict__ bprime)
{
  const unsigned tid = threadIdx.x, bx = blockIdx.x;
  if (bx < 512) {
    __shared__ float red[256];
    float partial = 0.f;
#pragma unroll
    for (int i = 0; i < 2; ++i) {
      unsigned d = i * 256u + tid;
      float iv = gamma[d] * rsqrtf(var[d] + 1e-5f);
      float w  = Wx[bx * 512u + d];
      Wxp[bx * 512u + d] = (unsigned short)f2bf(w * iv);
      partial += w * (beta[d] - mean[d] * iv);
    }
    red[tid] = partial; __syncthreads();
    for (unsigned s = 128; s > 0; s >>= 1) {
      if (tid < s) red[tid] += red[tid + s];
      __syncthreads();
    }
    if (tid == 0) bprime[bx] = red[0] + brnn[bx];
  } else {
    unsigned row = bx - 512;
#pragma unroll
    for (int i = 0; i < 2; ++i) {
      unsigned d = i * 256u + tid;
      Wfb[row * 512u + d] = (unsigned short)f2bf(Wffn[row * 512u + d]);
    }
  }
}

// ---------------------------------------------------------------------------
// convert x (fp32) -> bf16, row-major (RTOT, D)
// ---------------------------------------------------------------------------
__global__ __launch_bounds__(256) void convx_kernel(
    const float* __restrict__ x, unsigned short* __restrict__ Xbf)
{
  const unsigned total4 = RTOT * DD / 4;
  unsigned i = blockIdx.x * 256u + threadIdx.x;
  const unsigned stride = gridDim.x * 256u;
  const float4* __restrict__ x4 = (const float4*)x;
  for (; i < total4; i += stride) {
    float4 v = x4[i];
    unsigned short o0 = f2bf(v.x), o1 = f2bf(v.y), o2 = f2bf(v.z), o3 = f2bf(v.w);
    unsigned long long pack = (unsigned long long)o0 |
                              ((unsigned long long)o1 << 16) |
                              ((unsigned long long)o2 << 32) |
                              ((unsigned long long)o3 << 48);
    *(unsigned long long*)(Xbf + i * 4u) = pack;
  }
}

// ---------------------------------------------------------------------------
// GEMM1: U[r,e] = sum_d Xbf[r,d]*Wxp[e,d] + b'[e]   (fp32 out into d_out)
// 128x128 tile, BK=32, 256 thr (2x2 waves, 64x64/wave), m97-style structure.
// ---------------------------------------------------------------------------
__global__ __launch_bounds__(256) void gemm_u_kernel(
    const unsigned short* __restrict__ A, const unsigned short* __restrict__ Bw,
    const float* __restrict__ bias, float* __restrict__ U)
{
  __shared__ __align__(16) unsigned char lds[16384]; // A 8KB | B 8KB
  const unsigned tid = threadIdx.x;
  const unsigned lid = tid & 63u, wid = tid >> 6;
  const unsigned wr = wid >> 1, wc = wid & 1u;
  const unsigned rbase = blockIdx.x * 128u, nbase = blockIdx.y * 128u;

  f32x4 acc[4][4] = {};
  for (int kt = 0; kt < 16; ++kt) {
    __syncthreads();
#pragma unroll
    for (int i = 0; i < 2; ++i) {
      unsigned c = i * 256u + tid;
      const unsigned short* g = A + (rbase + (c >> 2)) * 512u + kt * 32u + (c & 3u) * 8u;
      __builtin_amdgcn_global_load_lds(AS1(g), AS3(lds + c * 16u), 16, 0, 0);
    }
#pragma unroll
    for (int i = 0; i < 2; ++i) {
      unsigned c = i * 256u + tid;
      const unsigned short* g = Bw + (nbase + (c >> 2)) * 512u + kt * 32u + (c & 3u) * 8u;
      __builtin_amdgcn_global_load_lds(AS1(g), AS3(lds + 8192u + c * 16u), 16, 0, 0);
    }
    __syncthreads();
    bf16x8 af[4], bfr[4];
#pragma unroll
    for (int mi = 0; mi < 4; ++mi)
      af[mi] = *(const bf16x8*)(lds + (wr * 64u + mi * 16u + (lid & 15u)) * 64u + (lid >> 4) * 16u);
#pragma unroll
    for (int ni = 0; ni < 4; ++ni)
      bfr[ni] = *(const bf16x8*)(lds + 8192u + (wc * 64u + ni * 16u + (lid & 15u)) * 64u + (lid >> 4) * 16u);
#pragma unroll
    for (int mi = 0; mi < 4; ++mi)
#pragma unroll
      for (int ni = 0; ni < 4; ++ni)
        acc[mi][ni] = MFMA16(af[mi], bfr[ni], acc[mi][ni], 0, 0, 0);
  }
#pragma unroll
  for (int mi = 0; mi < 4; ++mi)
#pragma unroll
    for (int ni = 0; ni < 4; ++ni) {
      unsigned e = nbase + wc * 64u + ni * 16u + (lid & 15u);
      float bb = bias[e];
#pragma unroll
      for (int j = 0; j < 4; ++j) {
        unsigned r = rbase + wr * 64u + mi * 16u + (lid >> 4) * 4u + j;
        U[r * 512u + e] = acc[mi][ni][j] + bb;
      }
    }
}

// ---------------------------------------------------------------------------
// Recurrence: 8 WGs x 256 thr. WG g owns cols [g*64, g*64+64); wave w owns its
// 16-col tile. Wh B-fragments are STATIONARY in VGPRs (loaded once). Per step:
// acquire-spin on counter, load h_{t-1} (16x512 bf16) from hbuf, 16 MFMAs in
// 2 chains, add u (fp32), tanh, write h_t slice to hbuf+Hs, release-add.
// ---------------------------------------------------------------------------
__global__ __launch_bounds__(256) void rnn_rec_kernel(
    const float* __restrict__ Wh, const float* __restrict__ U,
    unsigned short* __restrict__ Hs, unsigned short* __restrict__ hbuf,
    unsigned int* __restrict__ cnt)
{
  const unsigned tid = threadIdx.x, lid = tid & 63u, w = tid >> 6, g = blockIdx.x;
  const unsigned col = g * 64u + w * 16u + (lid & 15u);
  const unsigned kb = (lid >> 4) * 8u;

  // stationary B fragments: B[k][n] = Wh[n][k]
  bf16x8 bfrag[16];
#pragma unroll
  for (int kc = 0; kc < 16; ++kc) {
    bf16x8 tf;
#pragma unroll
    for (int j = 0; j < 8; ++j)
      tf[j] = (short)f2bf(Wh[col * 512u + kc * 32u + kb + j]);
    bfrag[kc] = tf;
  }

  for (unsigned st = 1; st <= LSEQ; ++st) {
    const unsigned tgt = WREC * (st - 1);
    unsigned guard = 0;
    while (__hip_atomic_load(cnt, __ATOMIC_ACQUIRE, __HIP_MEMORY_SCOPE_AGENT) < tgt) {
      if (++guard > 200000000u) break; // safety valve against hang
    }
    // u prefetch (independent of h)
    float uv[4];
#pragma unroll
    for (int j = 0; j < 4; ++j) {
      unsigned m = (lid >> 4) * 4u + j;
      uv[j] = U[(m * (unsigned)LSEQ + (st - 1)) * 512u + col];
    }
    const unsigned short* hb = hbuf + ((st - 1) & 1u) * 8192u;
    bf16x8 af[16];
#pragma unroll
    for (int kc = 0; kc < 16; ++kc)
      af[kc] = *(const bf16x8*)(hb + (lid & 15u) * 512u + kc * 32u + kb);
    f32x4 a0 = {}, a1 = {};
#pragma unroll
    for (int kc = 0; kc < 8; ++kc) a0 = MFMA16(af[kc], bfrag[kc], a0, 0, 0, 0);
#pragma unroll
    for (int kc = 8; kc < 16; ++kc) a1 = MFMA16(af[kc], bfrag[kc], a1, 0, 0, 0);

    unsigned short* hn = hbuf + (st & 1u) * 8192u;
#pragma unroll
    for (int j = 0; j < 4; ++j) {
      unsigned m = (lid >> 4) * 4u + j;
      float s = uv[j] + a0[j] + a1[j];
      float e2 = __expf(2.f * s);
      float h = 1.f - 2.f / (e2 + 1.f);       // tanh(s)
      unsigned short h16 = f2bf(h);
      hn[m * 512u + col] = h16;
      Hs[(m * (unsigned)LSEQ + (st - 1)) * 512u + col] = h16;
    }
    __syncthreads();  // drains vmcnt: all WG stores complete
    if (tid == 0)
      __hip_atomic_fetch_add(cnt, 1u, __ATOMIC_RELEASE, __HIP_MEMORY_SCOPE_AGENT);
  }
}

// ---------------------------------------------------------------------------
// GEMM3 + GLU + residual: Y[r,e]=sum_d Hs[r,d]*Wfb[e,d]+bffn[e]; paired g-tile
// at e+512; out[r,e] = a*sigmoid(g) + x[r,e]  (fp32, overwrites d_out)
// ---------------------------------------------------------------------------
__global__ __launch_bounds__(256) void gemm_ffn_kernel(
    const unsigned short* __restrict__ A, const unsigned short* __restrict__ Bw,
    const float* __restrict__ bffn, const float* __restrict__ x,
    float* __restrict__ out)
{
  __shared__ __align__(16) unsigned char lds[24576]; // A 8KB | Ba 8KB | Bg 8KB
  const unsigned tid = threadIdx.x;
  const unsigned lid = tid & 63u, wid = tid >> 6;
  const unsigned wr = wid >> 1, wc = wid & 1u;
  const unsigned rbase = blockIdx.x * 128u, nbase = blockIdx.y * 128u;

  f32x4 acc_a[4][4] = {}, acc_g[4][4] = {};
  for (int kt = 0; kt < 16; ++kt) {
    __syncthreads();
#pragma unroll
    for (int i = 0; i < 2; ++i) {
      unsigned c = i * 256u + tid;
      const unsigned short* ga = A + (rbase + (c >> 2)) * 512u + kt * 32u + (c & 3u) * 8u;
      __builtin_amdgcn_global_load_lds(AS1(ga), AS3(lds + c * 16u), 16, 0, 0);
      const unsigned short* gb = Bw + (nbase + (c >> 2)) * 512u + kt * 32u + (c & 3u) * 8u;
      __builtin_amdgcn_global_load_lds(AS1(gb), AS3(lds + 8192u + c * 16u), 16, 0, 0);
      const unsigned short* gg = Bw + (512u + nbase + (c >> 2)) * 512u + kt * 32u + (c & 3u) * 8u;
      __builtin_amdgcn_global_load_lds(AS1(gg), AS3(lds + 16384u + c * 16u), 16, 0, 0);
    }
    __syncthreads();
    bf16x8 af[4], ba[4], bg[4];
#pragma unroll
    for (int mi = 0; mi < 4; ++mi)
      af[mi] = *(const bf16x8*)(lds + (wr * 64u + mi * 16u + (lid & 15u)) * 64u + (lid >> 4) * 16u);
#pragma unroll
    for (int ni = 0; ni < 4; ++ni) {
      ba[ni] = *(const bf16x8*)(lds + 8192u  + (wc * 64u + ni * 16u + (lid & 15u)) * 64u + (lid >> 4) * 16u);
      bg[ni] = *(const bf16x8*)(lds + 16384u + (wc * 64u + ni * 16u + (lid & 15u)) * 64u + (lid >> 4) * 16u);
    }
#pragma unroll
    for (int mi = 0; mi < 4; ++mi)
#pragma unroll
      for (int ni = 0; ni < 4; ++ni) {
        acc_a[mi][ni] = MFMA16(af[mi], ba[ni], acc_a[mi][ni], 0, 0, 0);
        acc_g[mi][ni] = MFMA16(af[mi], bg[ni], acc_g[mi][ni], 0, 0, 0);
      }
  }
#pragma unroll
  for (int mi = 0; mi < 4; ++mi)
#pragma unroll
    for (int ni = 0; ni < 4; ++ni) {
      unsigned e = nbase + wc * 64u + ni * 16u + (lid & 15u);
      float bba = bffn[e], bbg = bffn[e + 512u];
#pragma unroll
      for (int j = 0; j < 4; ++j) {
        unsigned r = rbase + wr * 64u + mi * 16u + (lid >> 4) * 4u + j;
        float a  = acc_a[mi][ni][j] + bba;
        float gg = acc_g[mi][ni][j] + bbg;
        float sg = 1.f / (1.f + __expf(-gg));
        out[r * 512u + e] = a * sg + x[r * 512u + e];
      }
    }
}

// ---------------------------------------------------------------------------
extern "C" void kernel_launch(void* const* d_in, const int* in_sizes, int n_in,
                              void* d_out, int out_size, void* d_ws, size_t ws_size,
                              hipStream_t stream) {
  const float* x     = (const float*)d_in[0];
  const float* gamma = (const float*)d_in[1];
  const float* beta  = (const float*)d_in[2];
  const float* mean  = (const float*)d_in[3];
  const float* var   = (const float*)d_in[4];
  const float* Wx    = (const float*)d_in[5];
  const float* Wh    = (const float*)d_in[6];
  const float* brnn  = (const float*)d_in[7];
  const float* Wffn  = (const float*)d_in[8];
  const float* bffn  = (const float*)d_in[9];
  float* out = (float*)d_out;

  // workspace layout
  unsigned char* ws = (unsigned char*)d_ws;
  unsigned short* Hs   = (unsigned short*)(ws);                     // 32 MB
  unsigned short* Xbf  = (unsigned short*)(ws + (size_t)33554432);  // 32 MB
  unsigned short* Wxp  = (unsigned short*)(ws + (size_t)67108864);  // 512 KB
  unsigned short* Wfb  = (unsigned short*)(ws + (size_t)67633152);  // 1 MB
  float*          bpr  = (float*)        (ws + (size_t)68681728);   // 2 KB
  unsigned short* hbuf = (unsigned short*)(ws + (size_t)68683776);  // 32 KB
  unsigned int*   cnt  = (unsigned int*) (ws + (size_t)68716544);   // 64 B

  // U (input projection, fp32, 64MB) lives in d_out; overwritten by FFN epilogue
  float* U = out;

  prep_kernel<<<1536, 256, 0, stream>>>(Wx, gamma, beta, mean, var, brnn, Wffn,
                                        Wxp, Wfb, bpr);
  convx_kernel<<<2048, 256, 0, stream>>>(x, Xbf);
  hipMemsetAsync(hbuf, 0, 32768 + 64, stream);  // h0 = 0, cnt = 0
  gemm_u_kernel<<<dim3(256, 4), 256, 0, stream>>>(Xbf, Wxp, bpr, U);
  rnn_rec_kernel<<<WREC, 256, 0, stream>>>(Wh, U, Hs, hbuf, cnt);
  gemm_ffn_kernel<<<dim3(256, 4), 256, 0, stream>>>(Hs, Wfb, bffn, x, out);
}

// Round 2
// 7430.183 us; speedup vs baseline: 1.2255x; 1.2255x over previous
//
#include <hip/hip_runtime.h>
#include <math.h>

// Problem constants
#define DD   512
#define LSEQ 2048
#define NBAT 16
#define RTOT (NBAT * LSEQ)   // 32768 rows
#define WREC 8               // workgroups in recurrence

typedef __attribute__((ext_vector_type(8))) short bf16x8;
typedef __attribute__((ext_vector_type(4))) float f32x4;

#define AS1(p) ((const __attribute__((address_space(1))) void*)(p))
#define AS3(p) ((__attribute__((address_space(3))) void*)(p))
#define MFMA16 __builtin_amdgcn_mfma_f32_16x16x32_bf16

__device__ __forceinline__ unsigned short f2bf(float f) {
  unsigned u = __builtin_bit_cast(unsigned, f);
  u += 0x7fffu + ((u >> 16) & 1u);
  return (unsigned short)(u >> 16);
}

// ---------------------------------------------------------------------------
// prep: fold BN into Wx (Wx' = Wx*diag(inv), b' = Wx(beta-mean*inv)+b_rnn),
// convert Wffn to bf16.  blocks 0..511: Wx' row + b' ; blocks 512..1535: Wffn.
// ---------------------------------------------------------------------------
__global__ __launch_bounds__(256) void prep_kernel(
    const float* __restrict__ Wx, const float* __restrict__ gamma,
    const float* __restrict__ beta, const float* __restrict__ mean,
    const float* __restrict__ var, const float* __restrict__ brnn,
    const float* __restrict__ Wffn,
    unsigned short* __restrict__ Wxp, unsigned short* __restrict__ Wfb,
    float* __restrict__ bprime)
{
  const unsigned tid = threadIdx.x, bx = blockIdx.x;
  if (bx < 512) {
    __shared__ float red[256];
    float partial = 0.f;
#pragma unroll
    for (int i = 0; i < 2; ++i) {
      unsigned d = i * 256u + tid;
      float iv = gamma[d] * rsqrtf(var[d] + 1e-5f);
      float w  = Wx[bx * 512u + d];
      Wxp[bx * 512u + d] = (unsigned short)f2bf(w * iv);
      partial += w * (beta[d] - mean[d] * iv);
    }
    red[tid] = partial; __syncthreads();
    for (unsigned s = 128; s > 0; s >>= 1) {
      if (tid < s) red[tid] += red[tid + s];
      __syncthreads();
    }
    if (tid == 0) bprime[bx] = red[0] + brnn[bx];
  } else {
    unsigned row = bx - 512;
#pragma unroll
    for (int i = 0; i < 2; ++i) {
      unsigned d = i * 256u + tid;
      Wfb[row * 512u + d] = (unsigned short)f2bf(Wffn[row * 512u + d]);
    }
  }
}

// ---------------------------------------------------------------------------
// convert x (fp32) -> bf16, row-major (RTOT, D)
// ---------------------------------------------------------------------------
__global__ __launch_bounds__(256) void convx_kernel(
    const float* __restrict__ x, unsigned short* __restrict__ Xbf)
{
  const unsigned total4 = RTOT * DD / 4;
  unsigned i = blockIdx.x * 256u + threadIdx.x;
  const unsigned stride = gridDim.x * 256u;
  const float4* __restrict__ x4 = (const float4*)x;
  for (; i < total4; i += stride) {
    float4 v = x4[i];
    unsigned short o0 = f2bf(v.x), o1 = f2bf(v.y), o2 = f2bf(v.z), o3 = f2bf(v.w);
    unsigned long long pack = (unsigned long long)o0 |
                              ((unsigned long long)o1 << 16) |
                              ((unsigned long long)o2 << 32) |
                              ((unsigned long long)o3 << 48);
    *(unsigned long long*)(Xbf + i * 4u) = pack;
  }
}

// ---------------------------------------------------------------------------
// GEMM1: U[r,e] = sum_d Xbf[r,d]*Wxp[e,d] + b'[e]   (fp32 out into d_out)
// ---------------------------------------------------------------------------
__global__ __launch_bounds__(256) void gemm_u_kernel(
    const unsigned short* __restrict__ A, const unsigned short* __restrict__ Bw,
    const float* __restrict__ bias, float* __restrict__ U)
{
  __shared__ __align__(16) unsigned char lds[16384]; // A 8KB | B 8KB
  const unsigned tid = threadIdx.x;
  const unsigned lid = tid & 63u, wid = tid >> 6;
  const unsigned wr = wid >> 1, wc = wid & 1u;
  const unsigned rbase = blockIdx.x * 128u, nbase = blockIdx.y * 128u;

  f32x4 acc[4][4] = {};
  for (int kt = 0; kt < 16; ++kt) {
    __syncthreads();
#pragma unroll
    for (int i = 0; i < 2; ++i) {
      unsigned c = i * 256u + tid;
      const unsigned short* g = A + (rbase + (c >> 2)) * 512u + kt * 32u + (c & 3u) * 8u;
      __builtin_amdgcn_global_load_lds(AS1(g), AS3(lds + c * 16u), 16, 0, 0);
    }
#pragma unroll
    for (int i = 0; i < 2; ++i) {
      unsigned c = i * 256u + tid;
      const unsigned short* g = Bw + (nbase + (c >> 2)) * 512u + kt * 32u + (c & 3u) * 8u;
      __builtin_amdgcn_global_load_lds(AS1(g), AS3(lds + 8192u + c * 16u), 16, 0, 0);
    }
    __syncthreads();
    bf16x8 af[4], bfr[4];
#pragma unroll
    for (int mi = 0; mi < 4; ++mi)
      af[mi] = *(const bf16x8*)(lds + (wr * 64u + mi * 16u + (lid & 15u)) * 64u + (lid >> 4) * 16u);
#pragma unroll
    for (int ni = 0; ni < 4; ++ni)
      bfr[ni] = *(const bf16x8*)(lds + 8192u + (wc * 64u + ni * 16u + (lid & 15u)) * 64u + (lid >> 4) * 16u);
#pragma unroll
    for (int mi = 0; mi < 4; ++mi)
#pragma unroll
      for (int ni = 0; ni < 4; ++ni)
        acc[mi][ni] = MFMA16(af[mi], bfr[ni], acc[mi][ni], 0, 0, 0);
  }
#pragma unroll
  for (int mi = 0; mi < 4; ++mi)
#pragma unroll
    for (int ni = 0; ni < 4; ++ni) {
      unsigned e = nbase + wc * 64u + ni * 16u + (lid & 15u);
      float bb = bias[e];
#pragma unroll
      for (int j = 0; j < 4; ++j) {
        unsigned r = rbase + wr * 64u + mi * 16u + (lid >> 4) * 4u + j;
        U[r * 512u + e] = acc[mi][ni][j] + bb;
      }
    }
}

// ---------------------------------------------------------------------------
// Recurrence: 8 WGs x 256 thr. WG g owns cols [g*64, g*64+64); wave w its
// 16-col tile. Wh B-fragments STATIONARY in VGPRs. Per step:
//   wave0 polls per-WG monotonic flags (lanes 0-7, RELAXED) -> acquire fence
//   -> barrier -> load h_{t-1} (16KB from L3) + prefetch u_{t+1} -> 4 MFMA
//   chains -> tanh -> store h_t slice -> barrier -> tid0 RELEASE flag[g]
//   -> Hs stores (off critical path, drain during next spin).
// ---------------------------------------------------------------------------
__global__ __launch_bounds__(256) void rnn_rec_kernel(
    const float* __restrict__ Wh, const float* __restrict__ U,
    unsigned short* __restrict__ Hs, unsigned short* __restrict__ hbuf,
    unsigned int* __restrict__ flags)
{
  const unsigned tid = threadIdx.x, lid = tid & 63u, w = tid >> 6, g = blockIdx.x;
  const unsigned col = g * 64u + w * 16u + (lid & 15u);
  const unsigned kb = (lid >> 4) * 8u;

  // stationary B fragments: B[k][n] = Wh[n][k]
  bf16x8 bfrag[16];
#pragma unroll
  for (int kc = 0; kc < 16; ++kc) {
    bf16x8 tf;
#pragma unroll
    for (int j = 0; j < 8; ++j)
      tf[j] = (short)f2bf(Wh[col * 512u + kc * 32u + kb + j]);
    bfrag[kc] = tf;
  }

  // prefetch u for step 1 (t index 0)
  float uv[4];
#pragma unroll
  for (int j = 0; j < 4; ++j) {
    unsigned m = (lid >> 4) * 4u + j;
    uv[j] = U[(m * (unsigned)LSEQ + 0u) * 512u + col];
  }

  for (unsigned st = 1; st <= LSEQ; ++st) {
    const unsigned tgt = st - 1;
    if (w == 0) {
      unsigned guard = 0;
      while (true) {
        unsigned f = 0xffffffffu;
        if (lid < 8u)
          f = __hip_atomic_load(&flags[lid], __ATOMIC_RELAXED, __HIP_MEMORY_SCOPE_AGENT);
        unsigned long long b = __ballot(f >= tgt);
        if (b == ~0ull) break;
        if (++guard > 100000000u) break; // safety valve
      }
      __builtin_amdgcn_fence(__ATOMIC_ACQUIRE, "agent");
    }
    __syncthreads();

    // load h_{t-1} fragments (16 x 16B per lane = 16KB per WG)
    const unsigned short* hb = hbuf + ((st - 1) & 1u) * 8192u;
    bf16x8 af[16];
#pragma unroll
    for (int kc = 0; kc < 16; ++kc)
      af[kc] = *(const bf16x8*)(hb + (lid & 15u) * 512u + kc * 32u + kb);

    // prefetch u for next step (independent of h; hides HBM latency)
    float un[4];
    {
      unsigned tn = (st < LSEQ) ? st : (LSEQ - 1u);
#pragma unroll
      for (int j = 0; j < 4; ++j) {
        unsigned m = (lid >> 4) * 4u + j;
        un[j] = U[(m * (unsigned)LSEQ + tn) * 512u + col];
      }
    }

    f32x4 a0 = {}, a1 = {}, a2 = {}, a3 = {};
#pragma unroll
    for (int kc = 0; kc < 4; ++kc)  a0 = MFMA16(af[kc],      bfrag[kc],      a0, 0, 0, 0);
#pragma unroll
    for (int kc = 0; kc < 4; ++kc)  a1 = MFMA16(af[kc + 4],  bfrag[kc + 4],  a1, 0, 0, 0);
#pragma unroll
    for (int kc = 0; kc < 4; ++kc)  a2 = MFMA16(af[kc + 8],  bfrag[kc + 8],  a2, 0, 0, 0);
#pragma unroll
    for (int kc = 0; kc < 4; ++kc)  a3 = MFMA16(af[kc + 12], bfrag[kc + 12], a3, 0, 0, 0);

    unsigned short* hn = hbuf + (st & 1u) * 8192u;
    unsigned short h16[4];
#pragma unroll
    for (int j = 0; j < 4; ++j) {
      unsigned m = (lid >> 4) * 4u + j;
      float s = uv[j] + (a0[j] + a1[j]) + (a2[j] + a3[j]);
      float e2 = __expf(2.f * s);
      float h = 1.f - 2.f / (e2 + 1.f);       // tanh(s)
      h16[j] = f2bf(h);
      hn[m * 512u + col] = h16[j];
    }
    __syncthreads();  // all WG h stores complete (per-wave vmcnt drained)
    if (tid == 0)
      __hip_atomic_store(&flags[g], st, __ATOMIC_RELEASE, __HIP_MEMORY_SCOPE_AGENT);

    // history stores off the critical path (drain during next spin)
#pragma unroll
    for (int j = 0; j < 4; ++j) {
      unsigned m = (lid >> 4) * 4u + j;
      Hs[(m * (unsigned)LSEQ + (st - 1)) * 512u + col] = h16[j];
    }
#pragma unroll
    for (int j = 0; j < 4; ++j) uv[j] = un[j];
  }
}

// ---------------------------------------------------------------------------
// GEMM3 + GLU + residual: Y[r,e]=sum_d Hs[r,d]*Wfb[e,d]+bffn[e]; paired g-tile
// at e+512; out[r,e] = a*sigmoid(g) + x[r,e]  (fp32, overwrites d_out)
// ---------------------------------------------------------------------------
__global__ __launch_bounds__(256) void gemm_ffn_kernel(
    const unsigned short* __restrict__ A, const unsigned short* __restrict__ Bw,
    const float* __restrict__ bffn, const float* __restrict__ x,
    float* __restrict__ out)
{
  __shared__ __align__(16) unsigned char lds[24576]; // A 8KB | Ba 8KB | Bg 8KB
  const unsigned tid = threadIdx.x;
  const unsigned lid = tid & 63u, wid = tid >> 6;
  const unsigned wr = wid >> 1, wc = wid & 1u;
  const unsigned rbase = blockIdx.x * 128u, nbase = blockIdx.y * 128u;

  f32x4 acc_a[4][4] = {}, acc_g[4][4] = {};
  for (int kt = 0; kt < 16; ++kt) {
    __syncthreads();
#pragma unroll
    for (int i = 0; i < 2; ++i) {
      unsigned c = i * 256u + tid;
      const unsigned short* ga = A + (rbase + (c >> 2)) * 512u + kt * 32u + (c & 3u) * 8u;
      __builtin_amdgcn_global_load_lds(AS1(ga), AS3(lds + c * 16u), 16, 0, 0);
      const unsigned short* gb = Bw + (nbase + (c >> 2)) * 512u + kt * 32u + (c & 3u) * 8u;
      __builtin_amdgcn_global_load_lds(AS1(gb), AS3(lds + 8192u + c * 16u), 16, 0, 0);
      const unsigned short* gg = Bw + (512u + nbase + (c >> 2)) * 512u + kt * 32u + (c & 3u) * 8u;
      __builtin_amdgcn_global_load_lds(AS1(gg), AS3(lds + 16384u + c * 16u), 16, 0, 0);
    }
    __syncthreads();
    bf16x8 af[4], ba[4], bg[4];
#pragma unroll
    for (int mi = 0; mi < 4; ++mi)
      af[mi] = *(const bf16x8*)(lds + (wr * 64u + mi * 16u + (lid & 15u)) * 64u + (lid >> 4) * 16u);
#pragma unroll
    for (int ni = 0; ni < 4; ++ni) {
      ba[ni] = *(const bf16x8*)(lds + 8192u  + (wc * 64u + ni * 16u + (lid & 15u)) * 64u + (lid >> 4) * 16u);
      bg[ni] = *(const bf16x8*)(lds + 16384u + (wc * 64u + ni * 16u + (lid & 15u)) * 64u + (lid >> 4) * 16u);
    }
#pragma unroll
    for (int mi = 0; mi < 4; ++mi)
#pragma unroll
      for (int ni = 0; ni < 4; ++ni) {
        acc_a[mi][ni] = MFMA16(af[mi], ba[ni], acc_a[mi][ni], 0, 0, 0);
        acc_g[mi][ni] = MFMA16(af[mi], bg[ni], acc_g[mi][ni], 0, 0, 0);
      }
  }
#pragma unroll
  for (int mi = 0; mi < 4; ++mi)
#pragma unroll
    for (int ni = 0; ni < 4; ++ni) {
      unsigned e = nbase + wc * 64u + ni * 16u + (lid & 15u);
      float bba = bffn[e], bbg = bffn[e + 512u];
#pragma unroll
      for (int j = 0; j < 4; ++j) {
        unsigned r = rbase + wr * 64u + mi * 16u + (lid >> 4) * 4u + j;
        float a  = acc_a[mi][ni][j] + bba;
        float gg = acc_g[mi][ni][j] + bbg;
        float sg = 1.f / (1.f + __expf(-gg));
        out[r * 512u + e] = a * sg + x[r * 512u + e];
      }
    }
}

// ---------------------------------------------------------------------------
extern "C" void kernel_launch(void* const* d_in, const int* in_sizes, int n_in,
                              void* d_out, int out_size, void* d_ws, size_t ws_size,
                              hipStream_t stream) {
  const float* x     = (const float*)d_in[0];
  const float* gamma = (const float*)d_in[1];
  const float* beta  = (const float*)d_in[2];
  const float* mean  = (const float*)d_in[3];
  const float* var   = (const float*)d_in[4];
  const float* Wx    = (const float*)d_in[5];
  const float* Wh    = (const float*)d_in[6];
  const float* brnn  = (const float*)d_in[7];
  const float* Wffn  = (const float*)d_in[8];
  const float* bffn  = (const float*)d_in[9];
  float* out = (float*)d_out;

  // workspace layout
  unsigned char* ws = (unsigned char*)d_ws;
  unsigned short* Hs   = (unsigned short*)(ws);                     // 32 MB
  unsigned short* Xbf  = (unsigned short*)(ws + (size_t)33554432);  // 32 MB
  unsigned short* Wxp  = (unsigned short*)(ws + (size_t)67108864);  // 512 KB
  unsigned short* Wfb  = (unsigned short*)(ws + (size_t)67633152);  // 1 MB
  float*          bpr  = (float*)        (ws + (size_t)68681728);   // 2 KB
  unsigned short* hbuf = (unsigned short*)(ws + (size_t)68683776);  // 32 KB
  unsigned int*   flags= (unsigned int*) (ws + (size_t)68716544);   // 64 B

  // U (input projection, fp32, 64MB) lives in d_out; overwritten by FFN epilogue
  float* U = out;

  prep_kernel<<<1536, 256, 0, stream>>>(Wx, gamma, beta, mean, var, brnn, Wffn,
                                        Wxp, Wfb, bpr);
  convx_kernel<<<2048, 256, 0, stream>>>(x, Xbf);
  hipMemsetAsync(hbuf, 0, 32768 + 64, stream);  // h0 = 0, flags = 0
  gemm_u_kernel<<<dim3(256, 4), 256, 0, stream>>>(Xbf, Wxp, bpr, U);
  rnn_rec_kernel<<<WREC, 256, 0, stream>>>(Wh, U, Hs, hbuf, flags);
  gemm_ffn_kernel<<<dim3(256, 4), 256, 0, stream>>>(Hs, Wfb, bffn, x, out);
}

// Round 4
// 5381.002 us; speedup vs baseline: 1.6922x; 1.3808x over previous
//
#include <hip/hip_runtime.h>
#include <math.h>

// Problem constants
#define DD   512
#define LSEQ 2048
#define NBAT 16
#define RTOT (NBAT * LSEQ)   // 32768 rows
#define WREC 8               // workgroups in recurrence
#define RING 64              // h ring depth (1 MB; defeats consumer-L1 staleness)

typedef __attribute__((ext_vector_type(8))) short bf16x8;
typedef __attribute__((ext_vector_type(4))) float f32x4;

#define AS1(p) ((const __attribute__((address_space(1))) void*)(p))
#define AS3(p) ((__attribute__((address_space(3))) void*)(p))
#define MFMA16 __builtin_amdgcn_mfma_f32_16x16x32_bf16

__device__ __forceinline__ unsigned short f2bf(float f) {
  unsigned u = __builtin_bit_cast(unsigned, f);
  u += 0x7fffu + ((u >> 16) & 1u);
  return (unsigned short)(u >> 16);
}

// ---------------------------------------------------------------------------
// prep: fold BN into Wx (Wx' = Wx*diag(inv), b' = Wx(beta-mean*inv)+b_rnn),
// convert Wffn to bf16.  blocks 0..511: Wx' row + b' ; blocks 512..1535: Wffn.
// ---------------------------------------------------------------------------
__global__ __launch_bounds__(256) void prep_kernel(
    const float* __restrict__ Wx, const float* __restrict__ gamma,
    const float* __restrict__ beta, const float* __restrict__ mean,
    const float* __restrict__ var, const float* __restrict__ brnn,
    const float* __restrict__ Wffn,
    unsigned short* __restrict__ Wxp, unsigned short* __restrict__ Wfb,
    float* __restrict__ bprime)
{
  const unsigned tid = threadIdx.x, bx = blockIdx.x;
  if (bx < 512) {
    __shared__ float red[256];
    float partial = 0.f;
#pragma unroll
    for (int i = 0; i < 2; ++i) {
      unsigned d = i * 256u + tid;
      float iv = gamma[d] * rsqrtf(var[d] + 1e-5f);
      float w  = Wx[bx * 512u + d];
      Wxp[bx * 512u + d] = (unsigned short)f2bf(w * iv);
      partial += w * (beta[d] - mean[d] * iv);
    }
    red[tid] = partial; __syncthreads();
    for (unsigned s = 128; s > 0; s >>= 1) {
      if (tid < s) red[tid] += red[tid + s];
      __syncthreads();
    }
    if (tid == 0) bprime[bx] = red[0] + brnn[bx];
  } else {
    unsigned row = bx - 512;
#pragma unroll
    for (int i = 0; i < 2; ++i) {
      unsigned d = i * 256u + tid;
      Wfb[row * 512u + d] = (unsigned short)f2bf(Wffn[row * 512u + d]);
    }
  }
}

// ---------------------------------------------------------------------------
// convert x (fp32) -> bf16, row-major (RTOT, D)
// ---------------------------------------------------------------------------
__global__ __launch_bounds__(256) void convx_kernel(
    const float* __restrict__ x, unsigned short* __restrict__ Xbf)
{
  const unsigned total4 = RTOT * DD / 4;
  unsigned i = blockIdx.x * 256u + threadIdx.x;
  const unsigned stride = gridDim.x * 256u;
  const float4* __restrict__ x4 = (const float4*)x;
  for (; i < total4; i += stride) {
    float4 v = x4[i];
    unsigned short o0 = f2bf(v.x), o1 = f2bf(v.y), o2 = f2bf(v.z), o3 = f2bf(v.w);
    unsigned long long pack = (unsigned long long)o0 |
                              ((unsigned long long)o1 << 16) |
                              ((unsigned long long)o2 << 32) |
                              ((unsigned long long)o3 << 48);
    *(unsigned long long*)(Xbf + i * 4u) = pack;
  }
}

// ---------------------------------------------------------------------------
// GEMM1: U[r,e] = sum_d Xbf[r,d]*Wxp[e,d] + b'[e]   (fp32 out into d_out)
// ---------------------------------------------------------------------------
__global__ __launch_bounds__(256) void gemm_u_kernel(
    const unsigned short* __restrict__ A, const unsigned short* __restrict__ Bw,
    const float* __restrict__ bias, float* __restrict__ U)
{
  __shared__ __align__(16) unsigned char lds[16384]; // A 8KB | B 8KB
  const unsigned tid = threadIdx.x;
  const unsigned lid = tid & 63u, wid = tid >> 6;
  const unsigned wr = wid >> 1, wc = wid & 1u;
  const unsigned rbase = blockIdx.x * 128u, nbase = blockIdx.y * 128u;

  f32x4 acc[4][4] = {};
  for (int kt = 0; kt < 16; ++kt) {
    __syncthreads();
#pragma unroll
    for (int i = 0; i < 2; ++i) {
      unsigned c = i * 256u + tid;
      const unsigned short* g = A + (rbase + (c >> 2)) * 512u + kt * 32u + (c & 3u) * 8u;
      __builtin_amdgcn_global_load_lds(AS1(g), AS3(lds + c * 16u), 16, 0, 0);
    }
#pragma unroll
    for (int i = 0; i < 2; ++i) {
      unsigned c = i * 256u + tid;
      const unsigned short* g = Bw + (nbase + (c >> 2)) * 512u + kt * 32u + (c & 3u) * 8u;
      __builtin_amdgcn_global_load_lds(AS1(g), AS3(lds + 8192u + c * 16u), 16, 0, 0);
    }
    __syncthreads();
    bf16x8 af[4], bfr[4];
#pragma unroll
    for (int mi = 0; mi < 4; ++mi)
      af[mi] = *(const bf16x8*)(lds + (wr * 64u + mi * 16u + (lid & 15u)) * 64u + (lid >> 4) * 16u);
#pragma unroll
    for (int ni = 0; ni < 4; ++ni)
      bfr[ni] = *(const bf16x8*)(lds + 8192u + (wc * 64u + ni * 16u + (lid & 15u)) * 64u + (lid >> 4) * 16u);
#pragma unroll
    for (int mi = 0; mi < 4; ++mi)
#pragma unroll
      for (int ni = 0; ni < 4; ++ni)
        acc[mi][ni] = MFMA16(af[mi], bfr[ni], acc[mi][ni], 0, 0, 0);
  }
#pragma unroll
  for (int mi = 0; mi < 4; ++mi)
#pragma unroll
    for (int ni = 0; ni < 4; ++ni) {
      unsigned e = nbase + wc * 64u + ni * 16u + (lid & 15u);
      float bb = bias[e];
#pragma unroll
      for (int j = 0; j < 4; ++j) {
        unsigned r = rbase + wr * 64u + mi * 16u + (lid >> 4) * 4u + j;
        U[r * 512u + e] = acc[mi][ni][j] + bb;
      }
    }
}

// ---------------------------------------------------------------------------
// Recurrence, single-XCD, proven-primitive sync:
//   - 256 blocks; XCC_ID claim; first XCD to 8 claimants wins (CAS), rest exit.
//   - sync: ONE counter. release = RELAXED fetch_add(1) (no fence lowering!),
//     poll = RELAXED fetch_add(0) by lane 0 of every wave (atomics bypass L1
//     by nature; relaxed avoids buffer_wbl2/inv storms).
//   - h exchange: plain stores/loads on a 64-slot ring in XCD-shared L2.
//     Slot reuse distance = 63 steps x 16KB = 1MB >> 32KB L1 => no stale L1.
//   - happens-before: __syncthreads drains vmcnt (h in L2) -> release RMW ->
//     poller RMW sees it -> poller h-load hits same L2.
// ---------------------------------------------------------------------------
__global__ __launch_bounds__(256) void rnn_rec_kernel(
    const float* __restrict__ Wh, const float* __restrict__ U,
    unsigned short* __restrict__ Hs, unsigned short* __restrict__ ring,
    unsigned int* __restrict__ ctrl)
{
  __shared__ unsigned s_g;
  if (threadIdx.x == 0) {
    unsigned xcc;
    asm volatile("s_getreg_b32 %0, hwreg(HW_REG_XCC_ID)" : "=s"(xcc));
    xcc &= 7u;
    unsigned mygrp = 0xffffffffu;
    unsigned slot = __hip_atomic_fetch_add(&ctrl[16 + xcc], 1u, __ATOMIC_RELAXED,
                                           __HIP_MEMORY_SCOPE_AGENT);
    if (slot < 8u) {
      if (slot == 7u) {
        unsigned expected = 0u;
        __hip_atomic_compare_exchange_strong(&ctrl[24], &expected, xcc + 1u,
            __ATOMIC_RELEASE, __ATOMIC_RELAXED, __HIP_MEMORY_SCOPE_AGENT);
      }
      unsigned ch, gu = 0;
      do {
        ch = __hip_atomic_load(&ctrl[24], __ATOMIC_ACQUIRE, __HIP_MEMORY_SCOPE_AGENT);
      } while (ch == 0u && ++gu < 200000000u);
      if (ch == xcc + 1u) mygrp = slot;
    }
    s_g = mygrp;
  }
  __syncthreads();
  const unsigned g = s_g;
  if (g == 0xffffffffu) return;

  unsigned int* cnt = ctrl;  // single step counter
  const unsigned tid = threadIdx.x, lid = tid & 63u, w = tid >> 6;
  const unsigned col = g * 64u + w * 16u + (lid & 15u);
  const unsigned kb = (lid >> 4) * 8u;

  // stationary B fragments: B[k][n] = Wh[n][k]
  bf16x8 bfrag[16];
#pragma unroll
  for (int kc = 0; kc < 16; ++kc) {
    bf16x8 tf;
#pragma unroll
    for (int j = 0; j < 8; ++j)
      tf[j] = (short)f2bf(Wh[col * 512u + kc * 32u + kb + j]);
    bfrag[kc] = tf;
  }

  // prefetch u for step 1 (t index 0)
  float uv[4];
#pragma unroll
  for (int j = 0; j < 4; ++j) {
    unsigned m = (lid >> 4) * 4u + j;
    uv[j] = U[(m * (unsigned)LSEQ + 0u) * 512u + col];
  }

  unsigned spin_budget = 50000000u;  // cumulative valve: deadlock -> fast wrong
                                     // answer, never a 600s timeout
  for (unsigned st = 1; st <= LSEQ; ++st) {
    const unsigned tgt = WREC * (st - 1);
    // every wave polls via lane-0 relaxed RMW (never L1-stale), broadcast
    while (true) {
      unsigned c = 0u;
      if (lid == 0)
        c = __hip_atomic_fetch_add(cnt, 0u, __ATOMIC_RELAXED,
                                   __HIP_MEMORY_SCOPE_AGENT);
      c = __builtin_amdgcn_readfirstlane(c);
      if (c >= tgt) break;
      if (--spin_budget == 0u) break;
    }

    // load h_{t-1} from the ring (plain loads; same-XCD L2; L1 cold by ring)
    const unsigned short* hb = ring + ((st - 1u) & (RING - 1u)) * 8192u;
    bf16x8 af[16];
#pragma unroll
    for (int kc = 0; kc < 16; ++kc)
      af[kc] = *(const bf16x8*)(hb + (lid & 15u) * 512u + kc * 32u + kb);

    f32x4 a0 = {}, a1 = {}, a2 = {}, a3 = {};
#pragma unroll
    for (int kc = 0; kc < 4; ++kc)  a0 = MFMA16(af[kc],      bfrag[kc],      a0, 0, 0, 0);
#pragma unroll
    for (int kc = 0; kc < 4; ++kc)  a1 = MFMA16(af[kc + 4],  bfrag[kc + 4],  a1, 0, 0, 0);
#pragma unroll
    for (int kc = 0; kc < 4; ++kc)  a2 = MFMA16(af[kc + 8],  bfrag[kc + 8],  a2, 0, 0, 0);
#pragma unroll
    for (int kc = 0; kc < 4; ++kc)  a3 = MFMA16(af[kc + 12], bfrag[kc + 12], a3, 0, 0, 0);

    unsigned short* hn = ring + (st & (RING - 1u)) * 8192u;
    unsigned short h16[4];
#pragma unroll
    for (int j = 0; j < 4; ++j) {
      unsigned m = (lid >> 4) * 4u + j;
      float s = uv[j] + (a0[j] + a1[j]) + (a2[j] + a3[j]);
      float e2 = __expf(2.f * s);
      float h = 1.f - 2.f / (e2 + 1.f);       // tanh(s)
      h16[j] = f2bf(h);
      hn[m * 512u + col] = h16[j];
    }
    __syncthreads();  // per-wave vmcnt drained => all WG h-stores ack'd in L2
    if (tid == 0)
      __hip_atomic_fetch_add(cnt, 1u, __ATOMIC_RELAXED, __HIP_MEMORY_SCOPE_AGENT);

    // off-critical-path: history stores + next-u prefetch (drain during spin)
#pragma unroll
    for (int j = 0; j < 4; ++j) {
      unsigned m = (lid >> 4) * 4u + j;
      Hs[(m * (unsigned)LSEQ + (st - 1)) * 512u + col] = h16[j];
    }
    {
      unsigned tn = (st < LSEQ) ? st : (LSEQ - 1u);
#pragma unroll
      for (int j = 0; j < 4; ++j) {
        unsigned m = (lid >> 4) * 4u + j;
        uv[j] = U[(m * (unsigned)LSEQ + tn) * 512u + col];
      }
    }
  }
}

// ---------------------------------------------------------------------------
// GEMM3 + GLU + residual: Y[r,e]=sum_d Hs[r,d]*Wfb[e,d]+bffn[e]; paired g-tile
// at e+512; out[r,e] = a*sigmoid(g) + x[r,e]  (fp32, overwrites d_out)
// ---------------------------------------------------------------------------
__global__ __launch_bounds__(256) void gemm_ffn_kernel(
    const unsigned short* __restrict__ A, const unsigned short* __restrict__ Bw,
    const float* __restrict__ bffn, const float* __restrict__ x,
    float* __restrict__ out)
{
  __shared__ __align__(16) unsigned char lds[24576]; // A 8KB | Ba 8KB | Bg 8KB
  const unsigned tid = threadIdx.x;
  const unsigned lid = tid & 63u, wid = tid >> 6;
  const unsigned wr = wid >> 1, wc = wid & 1u;
  const unsigned rbase = blockIdx.x * 128u, nbase = blockIdx.y * 128u;

  f32x4 acc_a[4][4] = {}, acc_g[4][4] = {};
  for (int kt = 0; kt < 16; ++kt) {
    __syncthreads();
#pragma unroll
    for (int i = 0; i < 2; ++i) {
      unsigned c = i * 256u + tid;
      const unsigned short* ga = A + (rbase + (c >> 2)) * 512u + kt * 32u + (c & 3u) * 8u;
      __builtin_amdgcn_global_load_lds(AS1(ga), AS3(lds + c * 16u), 16, 0, 0);
      const unsigned short* gb = Bw + (nbase + (c >> 2)) * 512u + kt * 32u + (c & 3u) * 8u;
      __builtin_amdgcn_global_load_lds(AS1(gb), AS3(lds + 8192u + c * 16u), 16, 0, 0);
      const unsigned short* gg = Bw + (512u + nbase + (c >> 2)) * 512u + kt * 32u + (c & 3u) * 8u;
      __builtin_amdgcn_global_load_lds(AS1(gg), AS3(lds + 16384u + c * 16u), 16, 0, 0);
    }
    __syncthreads();
    bf16x8 af[4], ba[4], bg[4];
#pragma unroll
    for (int mi = 0; mi < 4; ++mi)
      af[mi] = *(const bf16x8*)(lds + (wr * 64u + mi * 16u + (lid & 15u)) * 64u + (lid >> 4) * 16u);
#pragma unroll
    for (int ni = 0; ni < 4; ++ni) {
      ba[ni] = *(const bf16x8*)(lds + 8192u  + (wc * 64u + ni * 16u + (lid & 15u)) * 64u + (lid >> 4) * 16u);
      bg[ni] = *(const bf16x8*)(lds + 16384u + (wc * 64u + ni * 16u + (lid & 15u)) * 64u + (lid >> 4) * 16u);
    }
#pragma unroll
    for (int mi = 0; mi < 4; ++mi)
#pragma unroll
      for (int ni = 0; ni < 4; ++ni) {
        acc_a[mi][ni] = MFMA16(af[mi], ba[ni], acc_a[mi][ni], 0, 0, 0);
        acc_g[mi][ni] = MFMA16(af[mi], bg[ni], acc_g[mi][ni], 0, 0, 0);
      }
  }
#pragma unroll
  for (int mi = 0; mi < 4; ++mi)
#pragma unroll
    for (int ni = 0; ni < 4; ++ni) {
      unsigned e = nbase + wc * 64u + ni * 16u + (lid & 15u);
      float bba = bffn[e], bbg = bffn[e + 512u];
#pragma unroll
      for (int j = 0; j < 4; ++j) {
        unsigned r = rbase + wr * 64u + mi * 16u + (lid >> 4) * 4u + j;
        float a  = acc_a[mi][ni][j] + bba;
        float gg = acc_g[mi][ni][j] + bbg;
        float sg = 1.f / (1.f + __expf(-gg));
        out[r * 512u + e] = a * sg + x[r * 512u + e];
      }
    }
}

// ---------------------------------------------------------------------------
extern "C" void kernel_launch(void* const* d_in, const int* in_sizes, int n_in,
                              void* d_out, int out_size, void* d_ws, size_t ws_size,
                              hipStream_t stream) {
  const float* x     = (const float*)d_in[0];
  const float* gamma = (const float*)d_in[1];
  const float* beta  = (const float*)d_in[2];
  const float* mean  = (const float*)d_in[3];
  const float* var   = (const float*)d_in[4];
  const float* Wx    = (const float*)d_in[5];
  const float* Wh    = (const float*)d_in[6];
  const float* brnn  = (const float*)d_in[7];
  const float* Wffn  = (const float*)d_in[8];
  const float* bffn  = (const float*)d_in[9];
  float* out = (float*)d_out;

  // workspace layout
  unsigned char* ws = (unsigned char*)d_ws;
  unsigned short* Hs   = (unsigned short*)(ws);                     // 32 MB
  unsigned short* Xbf  = (unsigned short*)(ws + (size_t)33554432);  // 32 MB
  unsigned short* Wxp  = (unsigned short*)(ws + (size_t)67108864);  // 512 KB
  unsigned short* Wfb  = (unsigned short*)(ws + (size_t)67633152);  // 1 MB
  float*          bpr  = (float*)        (ws + (size_t)68681728);   // 2 KB
  // ring (1 MB) + ctrl (128 B) ALIAS the Xbf region: Xbf is dead after
  // gemm_u, and the memsets below are stream-ordered after gemm_u.
  unsigned short* ring = (unsigned short*)(ws + (size_t)33554432);
  unsigned int*   ctrl = (unsigned int*)  (ws + (size_t)33554432 + 1048576);

  // U (input projection, fp32, 64MB) lives in d_out; overwritten by FFN epilogue
  float* U = out;

  prep_kernel<<<1536, 256, 0, stream>>>(Wx, gamma, beta, mean, var, brnn, Wffn,
                                        Wxp, Wfb, bpr);
  convx_kernel<<<2048, 256, 0, stream>>>(x, Xbf);
  gemm_u_kernel<<<dim3(256, 4), 256, 0, stream>>>(Xbf, Wxp, bpr, U);
  hipMemsetAsync(ring, 0, 16384, stream);  // h0 = 0 (ring slot 0)
  hipMemsetAsync(ctrl, 0, 128, stream);    // cnt, claim[8], chosen = 0
  rnn_rec_kernel<<<256, 256, 0, stream>>>(Wh, U, Hs, ring, ctrl);
  gemm_ffn_kernel<<<dim3(256, 4), 256, 0, stream>>>(Hs, Wfb, bffn, x, out);
}